// Round 1
// 242.731 us; speedup vs baseline: 1.0170x; 1.0170x over previous
//
#include <hip/hip_runtime.h>
#include <math.h>

#define Bc 64
#define Nc 4
#define Ac 1024
#define Oc 128
#define Dc 256
#define Qc 256
#define Hc 128
#define BN (Bc*Nc)

using f4     = __attribute__((ext_vector_type(4))) float;
using f32x4  = __attribute__((ext_vector_type(4))) float;
using short8 = __attribute__((ext_vector_type(8))) short;
using us4    = __attribute__((ext_vector_type(4))) unsigned short;

__device__ inline float decode_t(const void* p) {
    int i = *(const int*)p;
    if (i >= 1 && i <= 1000000) return (float)i;
    return __int_as_float(i);
}

// round-to-nearest-even fp32 -> bf16
__device__ inline unsigned short bf16_rne(float x) {
    unsigned u = __builtin_bit_cast(unsigned, x);
    u += 0x7FFFu + ((u >> 16) & 1u);
    return (unsigned short)(u >> 16);
}

// split fp32 -> truncated bf16 hi + bf16(residual) lo.  x ~= hi + lo
__device__ inline void split_bf16(float x, unsigned short& hi, unsigned short& lo) {
    unsigned u = __builtin_bit_cast(unsigned, x);
    hi = (unsigned short)(u >> 16);
    float hif = __builtin_bit_cast(float, u & 0xFFFF0000u);
    float lof = x - hif;
    lo = (unsigned short)(__builtin_bit_cast(unsigned, lof) >> 16);
}

// ---------------------------------------------------------------------------
// prep_M: Mt[b][h][o] = sum_d W1[d][h] * obj[b][o][d]  (transposed, [n][k])
// bf16 hi/lo output. grid (4,2,64): 32h x 64o tile, 256 thr, double-buffered K.
// ---------------------------------------------------------------------------
__global__ __launch_bounds__(256) void prep_M_kernel(
    const float* __restrict__ obj, const float* __restrict__ W1,
    unsigned short* __restrict__ Mt_hi, unsigned short* __restrict__ Mt_lo)
{
    __shared__ float w_s[32][36];     // [k][h]
    __shared__ float obj_sT[32][68];  // [k][o]

    const int t  = threadIdx.x;
    const int tx = t & 15;    // o = o0 + tx*4 + j
    const int ty = t >> 4;    // h = h0 + ty*2 + i
    const int h0 = blockIdx.x * 32;
    const int o0 = blockIdx.y * 64;
    const int b  = blockIdx.z;
    const int r8 = t >> 3, c8 = t & 7;

    const float* objb = obj + ((size_t)b * Oc + o0) * Dc;

    float acc[2][4];
    #pragma unroll
    for (int i = 0; i < 2; i++)
        #pragma unroll
        for (int j = 0; j < 4; j++) acc[i][j] = 0.f;

    f4 wv  = *(const f4*)(W1 + (size_t)r8 * Hc + h0 + c8 * 4);
    f4 ov0 = *(const f4*)(objb + (size_t)r8 * Dc + c8 * 4);
    f4 ov1 = *(const f4*)(objb + (size_t)(r8 + 32) * Dc + c8 * 4);

    for (int ko = 0; ko < 8; ++ko) {
        *(f4*)&w_s[r8][c8 * 4] = wv;
        obj_sT[c8 * 4 + 0][r8] = ov0[0];
        obj_sT[c8 * 4 + 1][r8] = ov0[1];
        obj_sT[c8 * 4 + 2][r8] = ov0[2];
        obj_sT[c8 * 4 + 3][r8] = ov0[3];
        obj_sT[c8 * 4 + 0][r8 + 32] = ov1[0];
        obj_sT[c8 * 4 + 1][r8 + 32] = ov1[1];
        obj_sT[c8 * 4 + 2][r8 + 32] = ov1[2];
        obj_sT[c8 * 4 + 3][r8 + 32] = ov1[3];
        __syncthreads();
        if (ko < 7) {
            wv  = *(const f4*)(W1 + (size_t)((ko + 1) * 32 + r8) * Hc + h0 + c8 * 4);
            ov0 = *(const f4*)(objb + (size_t)r8 * Dc + (ko + 1) * 32 + c8 * 4);
            ov1 = *(const f4*)(objb + (size_t)(r8 + 32) * Dc + (ko + 1) * 32 + c8 * 4);
        }
        #pragma unroll 4
        for (int k = 0; k < 32; k++) {
            float a0 = w_s[k][ty * 2];
            float a1 = w_s[k][ty * 2 + 1];
            f4 bv = *(const f4*)&obj_sT[k][tx * 4];
            #pragma unroll
            for (int j = 0; j < 4; j++) {
                acc[0][j] += a0 * bv[j];
                acc[1][j] += a1 * bv[j];
            }
        }
        __syncthreads();
    }

    #pragma unroll
    for (int i = 0; i < 2; i++) {
        us4 hi, lo;
        #pragma unroll
        for (int j = 0; j < 4; j++) {
            unsigned short h16, l16;
            split_bf16(acc[i][j], h16, l16);
            hi[j] = h16; lo[j] = l16;
        }
        size_t ofs = ((size_t)b * Hc + h0 + ty * 2 + i) * Oc + o0 + tx * 4;
        *(us4*)(Mt_hi + ofs) = hi;
        *(us4*)(Mt_lo + ofs) = lo;
    }
}

// ---------------------------------------------------------------------------
// prep_qb: qb[bn,h] = q[bn,:] @ W1q + b1[h]
// ---------------------------------------------------------------------------
__global__ __launch_bounds__(512) void prep_qb_kernel(
    const float* __restrict__ q, const float* __restrict__ W1,
    const float* __restrict__ b1, float* __restrict__ qb)
{
    __shared__ float qs[256];
    __shared__ float red[4][128];
    const int t = threadIdx.x;
    const int bn = blockIdx.x;

    if (t < 256) qs[t] = q[bn * Qc + t];
    __syncthreads();

    const int h = t & 127, kq = t >> 7;
    float acc = 0.f;
    const float* w = W1 + (size_t)(Dc + kq * 64) * Hc + h;
    #pragma unroll 8
    for (int d = 0; d < 64; ++d)
        acc += qs[kq * 64 + d] * w[(size_t)d * Hc];
    red[kq][h] = acc;
    __syncthreads();

    if (t < 128)
        qb[bn * Hc + t] = b1[t] + red[0][t] + red[1][t] + red[2][t] + red[3][t];
}

// ---------------------------------------------------------------------------
// main_half: grid (512) = 2 blocks per bn, each owns 512 rows (8 tiles of 64).
// 512 thr (8 waves) -> 2 blocks/CU resident (LDS ~23KB, VGPR<=128): barrier
// and vmcnt(0) stalls of one block are absorbed by the other block's waves.
// Wave w owns h-cols w*16..w*16+15 over all 64 rows of the tile.
// Softmax decomposes: block accumulates partial Z and partial sum_a e*att1
// locally; finalize kernel combines the two halves. No atomics.
// ---------------------------------------------------------------------------
__global__ __launch_bounds__(512, 4) void main_half_kernel(
    const float* __restrict__ att1, const int* __restrict__ tags,
    const unsigned short* __restrict__ Mt_hi, const unsigned short* __restrict__ Mt_lo,
    const float* __restrict__ qb, const float* __restrict__ W2,
    const float* __restrict__ b2, const void* __restrict__ tptr,
    float* __restrict__ out_part, float* __restrict__ z_part)
{
    __shared__ unsigned short A_s[64][136];   // single-buffer bf16 tile, 17.4 KB
    __shared__ float part2[64][9];            // logit partials, +1 pad
    __shared__ float part3[4][132];           // phase-3 partials
    __shared__ float e_s[64];
    __shared__ float qb_s[128], w2_s[128];

    const int t    = threadIdx.x;
    const int lane = t & 63;
    const int wave = t >> 6;          // 0..7
    const int l15  = lane & 15;
    const int quad = lane >> 4;
    const int blk  = blockIdx.x;      // 0..511
    const int bn   = blk >> 1;
    const int half = blk & 1;
    const int b    = bn >> 2;
    const int hw   = wave * 16;       // h-group base

    const float* att_half = att1 + ((size_t)bn * Ac + half * 512) * Oc;

    // ---- prologue: tile-0 staging loads (HBM) ----
    f4 sv[4];
    #pragma unroll
    for (int s = 0; s < 4; s++) {
        int idx = t + 512 * s;
        sv[s] = *(const f4*)(att_half + (size_t)idx * 4);
    }

    // ---- B fragments (hi/lo), once per block ----
    const size_t brow = ((size_t)b * Hc + hw + l15) * Oc;
    short8 Bh[4], Bl[4];
    #pragma unroll
    for (int ks = 0; ks < 4; ks++) {
        const int ko = ks * 32 + quad * 8;
        Bh[ks] = *(const short8*)(Mt_hi + brow + ko);
        Bl[ks] = *(const short8*)(Mt_lo + brow + ko);
    }

    if (t < 128) { qb_s[t] = qb[bn * Hc + t]; w2_s[t] = W2[t]; }
    int tg_cur = (t < 64) ? tags[(size_t)bn * Ac + half * 512 + t] : 0;
    const float b2v  = b2[0];
    const float tval = decode_t(tptr);

    float z_reg = 0.f, out_reg = 0.f;

    for (int tile = 0; tile < 8; ++tile) {
        const float* tile_ptr = att_half + (size_t)tile * 64 * Oc;

        // ---- merged: reduce prev tile's part3, convert staged fp32 -> bf16 ----
        if (tile > 0 && t < 128) {
            float s = 0.f;
            #pragma unroll
            for (int g = 0; g < 4; g++) s += part3[g][t];
            out_reg += s;
        }
        #pragma unroll
        for (int s = 0; s < 4; s++) {
            int idx = t + 512 * s;
            int r = idx >> 5, c4 = idx & 31;
            us4 h4;
            #pragma unroll
            for (int j = 0; j < 4; j++) h4[j] = bf16_rne(sv[s][j]);
            *(us4*)&A_s[r][c4 * 4] = h4;
        }
        __syncthreads();

        // ---- prefetch next tile (in flight through all of this tile) ----
        int tg_next = 0;
        if (tile < 7) {
            const float* np = tile_ptr + 64 * Oc;
            #pragma unroll
            for (int s = 0; s < 4; s++) {
                int idx = t + 512 * s;
                sv[s] = *(const f4*)(np + (size_t)idx * 4);
            }
            if (t < 64) tg_next = tags[(size_t)bn * Ac + half * 512 + (tile + 1) * 64 + t];
        }

        // ---- MFMA: A_rne * (Bhi + Blo) ----
        f32x4 acc[4];
        #pragma unroll
        for (int i = 0; i < 4; i++) acc[i] = (f32x4)(0.f);
        #pragma unroll
        for (int ks = 0; ks < 4; ks++) {
            const int ko = ks * 32 + quad * 8;
            #pragma unroll
            for (int i = 0; i < 4; i++) {
                short8 ah = *(const short8*)&A_s[i * 16 + l15][ko];
                acc[i] = __builtin_amdgcn_mfma_f32_16x16x32_bf16(ah, Bh[ks], acc[i], 0, 0, 0);
                acc[i] = __builtin_amdgcn_mfma_f32_16x16x32_bf16(ah, Bl[ks], acc[i], 0, 0, 0);
            }
        }

        // ---- epilogue: +qb, relu, *W2, reduce over the wave's 16 h ----
        // C/D layout: col(h) = l15, row(a) = i*16 + quad*4 + r
        {
            const float qbv = qb_s[hw + l15], w2v = w2_s[hw + l15];
            float p[4][4];
            #pragma unroll
            for (int i = 0; i < 4; i++)
                #pragma unroll
                for (int r = 0; r < 4; r++) {
                    float v = acc[i][r] + qbv;
                    v = v > 0.f ? v : 0.f;
                    p[i][r] = v * w2v;
                }
            #pragma unroll
            for (int m = 1; m <= 8; m <<= 1)
                #pragma unroll
                for (int i = 0; i < 4; i++)
                    #pragma unroll
                    for (int r = 0; r < 4; r++)
                        p[i][r] += __shfl_xor(p[i][r], m);
            if (l15 == 0) {
                #pragma unroll
                for (int i = 0; i < 4; i++)
                    #pragma unroll
                    for (int r = 0; r < 4; r++)
                        part2[i * 16 + quad * 4 + r][wave] = p[i][r];
            }
        }
        __syncthreads();

        // ---- masked exp; accumulate Z in registers (wave 0 only) ----
        if (t < 64) {
            float sum = b2v;
            #pragma unroll
            for (int x = 0; x < 8; x++) sum += part2[t][x];
            float logit = sum / tval;
            float e = (tg_cur > 0) ? __expf(logit) : 0.f;
            e_s[t] = e;
            z_reg += e;
        }
        __syncthreads();

        // ---- phase 3: partial out[o] += sum_a e[a]*att1[a,o]  (L2-hot) ----
        {
            const int o = t & 127;
            const int g = t >> 7;   // 0..3, 16 rows each
            const float* ab = tile_ptr + (size_t)(g * 16) * Oc + o;
            float accum = 0.f;
            #pragma unroll
            for (int a = 0; a < 16; a++)
                accum += e_s[g * 16 + a] * ab[(size_t)a * Oc];
            part3[g][o] = accum;
        }
        __syncthreads();
        tg_cur = tg_next;
    }

    // ---- finalize partials: out_part, z_part for this half ----
    if (t < 128) {
        float s = 0.f;
        #pragma unroll
        for (int g = 0; g < 4; g++) s += part3[g][t];
        out_reg += s;
        out_part[(size_t)blk * 128 + t] = out_reg;
    }
    if (t < 64) {   // all z_reg live in wave 0
        float z = z_reg;
        #pragma unroll
        for (int off = 32; off > 0; off >>= 1) z += __shfl_down(z, off);
        if (t == 0) z_part[blk] = z;
    }
}

// ---------------------------------------------------------------------------
// finalize: out[bn,o] = (P0+P1)/(Z0+Z1)
// ---------------------------------------------------------------------------
__global__ __launch_bounds__(128) void finalize_kernel(
    const float* __restrict__ out_part, const float* __restrict__ z_part,
    float* __restrict__ out)
{
    const int bn = blockIdx.x;
    const int t  = threadIdx.x;
    const float Z = z_part[bn * 2] + z_part[bn * 2 + 1];
    const float v = out_part[(size_t)(bn * 2) * 128 + t]
                  + out_part[(size_t)(bn * 2 + 1) * 128 + t];
    out[(size_t)bn * 128 + t] = v / Z;
}

extern "C" void kernel_launch(void* const* d_in, const int* in_sizes, int n_in,
                              void* d_out, int out_size, void* d_ws, size_t ws_size,
                              hipStream_t stream)
{
    (void)in_sizes; (void)n_in; (void)out_size; (void)ws_size;

    const float* q    = (const float*)d_in[0];
    const float* att1 = (const float*)d_in[1];
    const float* obj  = (const float*)d_in[2];
    const int*   tags = (const int*)d_in[3];
    const float* W1   = (const float*)d_in[4];
    const float* b1   = (const float*)d_in[5];
    const float* W2   = (const float*)d_in[6];
    const float* b2   = (const float*)d_in[7];
    const void*  tptr = (const void*)d_in[8];
    float* out = (float*)d_out;

    char* wsb = (char*)d_ws;
    unsigned short* Mt_hi = (unsigned short*)wsb;                          // 2 MB
    unsigned short* Mt_lo = (unsigned short*)(wsb + (size_t)2*1024*1024);  // 2 MB
    float* qbuf     = (float*)(wsb + (size_t)4*1024*1024);   // BN*H floats (128 KB)
    float* out_part = (float*)(wsb + (size_t)5*1024*1024);   // 2*BN*O floats (256 KB)
    float* z_part   = (float*)(wsb + (size_t)6*1024*1024);   // 2*BN floats

    prep_M_kernel<<<dim3(4, 2, Bc), 256, 0, stream>>>(obj, W1, Mt_hi, Mt_lo);
    prep_qb_kernel<<<dim3(BN), 512, 0, stream>>>(q, W1, b1, qbuf);
    main_half_kernel<<<dim3(2 * BN), 512, 0, stream>>>(att1, tags, Mt_hi, Mt_lo,
                                                       qbuf, W2, b2, tptr,
                                                       out_part, z_part);
    finalize_kernel<<<dim3(BN), 128, 0, stream>>>(out_part, z_part, out);
}